// Round 2
// baseline (299.937 us; speedup 1.0000x reference)
//
#include <hip/hip_runtime.h>
#include <hip/hip_bf16.h>

// Problem constants (fixed instance):
#define NPL   16384        // nodes per level
#define DIM   64
#define CPN   8            // children per node
#define EPL   (NPL * CPN)  // edges per level block = 131072
#define NLEV  8

__device__ __forceinline__ float bf2f(unsigned short u) {
    return __uint_as_float(((unsigned int)u) << 16);
}
__device__ __forceinline__ unsigned short f2bf(float f) {
    // round-to-nearest-even float32 -> bf16
    unsigned int u = __float_as_uint(f);
    unsigned int r = (u + 0x7FFFu + ((u >> 16) & 1u)) >> 16;
    return (unsigned short)r;
}

// ---- dtype detection: are the float tensors stored as float32 or bf16? ----
// Real float32 ~N(0,1): exponent field in ~[100,130].
// bf16-packed pairs read as float32: exponent field lands near 240..255 / ~0.
__global__ void detect_kernel(const unsigned int* __restrict__ x_words,
                              int* __restrict__ flag)
{
    if (threadIdx.x == 0 && blockIdx.x == 0) {
        int cnt = 0;
        for (int i = 0; i < 64; ++i) {
            unsigned int w = x_words[i];
            unsigned int e = (w >> 23) & 0xFFu;
            if (e >= 64u && e <= 191u) ++cnt;   // plausible float32 magnitude
        }
        *flag = (cnt >= 32) ? 1 : 0;            // 1 = float32, 0 = bf16
    }
}

// ---- generic element / row access ----
template<bool F32>
__device__ __forceinline__ float ld_elem(const void* p, long i) {
    if (F32) return ((const float*)p)[i];
    else     return bf2f(((const unsigned short*)p)[i]);
}
template<bool F32>
__device__ __forceinline__ void st_elem(void* p, long i, float v) {
    if (F32) ((float*)p)[i] = v;
    else     ((unsigned short*)p)[i] = f2bf(v);
}
template<bool F32>
__device__ __forceinline__ void load_row(float* dst, const void* W, int row) {
    if (F32) {
        const float4* p = (const float4*)((const float*)W + row * DIM);
        #pragma unroll
        for (int q = 0; q < DIM / 4; ++q) {
            float4 v = p[q];
            dst[q*4+0] = v.x; dst[q*4+1] = v.y;
            dst[q*4+2] = v.z; dst[q*4+3] = v.w;
        }
    } else {
        const uint4* p = (const uint4*)((const unsigned short*)W + row * DIM);
        #pragma unroll
        for (int q = 0; q < DIM / 8; ++q) {
            uint4 v = p[q];
            const unsigned int pw[4] = {v.x, v.y, v.z, v.w};
            #pragma unroll
            for (int t = 0; t < 4; ++t) {
                dst[q*8 + 2*t + 0] = __uint_as_float(pw[t] << 16);
                dst[q*8 + 2*t + 1] = __uint_as_float(pw[t] & 0xffff0000u);
            }
        }
    }
}

// Wave (64 lanes) = one node; lane = output dim d.
// out[g][d] = (lvl==0) ? x[g]·Wr[d]
//           : tanh( x[g]·Wr[d] + (sum_j out[child_j])·Wl[d] + bl[d] )
template<bool F32>
__device__ __forceinline__ void level_body(
    const void* __restrict__ x, const int* __restrict__ src,
    const void* __restrict__ Wl, const void* __restrict__ bl,
    const void* __restrict__ Wr, void* __restrict__ out,
    int lvl, int lane, int w, float (*sIn1)[DIM], float (*sIn2)[DIM], int blockId)
{
    float wr[DIM], wl[DIM];
    load_row<F32>(wr, Wr, lane);
    load_row<F32>(wl, Wl, lane);
    const float bias = (lvl > 0) ? ld_elem<F32>(bl, lane) : 0.0f;

    const int nodeBase = blockId * 16;
    for (int c = 0; c < 4; ++c) {
        const int p = nodeBase + c * 4 + w;      // node index within level
        const long g = (long)lvl * NPL + p;      // global node id

        float xv  = ld_elem<F32>(x, g * DIM + lane);
        float agg = 0.0f;
        if (lvl > 0) {
            const int* e = src + (long)(lvl - 1) * EPL + (long)p * CPN;
            #pragma unroll
            for (int j = 0; j < CPN; ++j) {
                const long s = e[j];             // child global id (level lvl-1)
                agg += ld_elem<F32>(out, s * DIM + lane);  // coalesced per wave
            }
        }
        sIn1[w][lane] = xv;
        sIn2[w][lane] = agg;
        __syncthreads();

        float acc = bias;
        #pragma unroll
        for (int k4 = 0; k4 < DIM / 4; ++k4) {
            const float4 a = *(const float4*)&sIn1[w][k4 * 4]; // uniform broadcast
            const float4 b = *(const float4*)&sIn2[w][k4 * 4];
            acc += a.x * wr[k4*4+0] + b.x * wl[k4*4+0];
            acc += a.y * wr[k4*4+1] + b.y * wl[k4*4+1];
            acc += a.z * wr[k4*4+2] + b.z * wl[k4*4+2];
            acc += a.w * wr[k4*4+3] + b.w * wl[k4*4+3];
        }
        if (lvl > 0) acc = tanhf(acc);
        st_elem<F32>(out, g * DIM + lane, acc);
        __syncthreads();
    }
}

__global__ __launch_bounds__(256) void level_kernel(
    const void* __restrict__ x, const int* __restrict__ src,
    const void* __restrict__ Wl, const void* __restrict__ bl,
    const void* __restrict__ Wr, void* __restrict__ out,
    const int* __restrict__ flag, int lvl)
{
    __shared__ __align__(16) float sIn1[4][DIM];
    __shared__ __align__(16) float sIn2[4][DIM];
    const int lane = threadIdx.x & 63;
    const int w    = threadIdx.x >> 6;
    if (*flag)
        level_body<true >(x, src, Wl, bl, Wr, out, lvl, lane, w, sIn1, sIn2, blockIdx.x);
    else
        level_body<false>(x, src, Wl, bl, Wr, out, lvl, lane, w, sIn1, sIn2, blockIdx.x);
}

extern "C" void kernel_launch(void* const* d_in, const int* in_sizes, int n_in,
                              void* d_out, int out_size, void* d_ws, size_t ws_size,
                              hipStream_t stream) {
    const void* x  = d_in[0];                 // [131072,64] f32 or bf16
    const int*  ei = (const int*)d_in[1];     // [2, 917504] int32
    const void* Wl = d_in[2];                 // [64,64]
    const void* bl = d_in[3];                 // [64]
    const void* Wr = d_in[4];                 // [64,64]
    void* out = d_out;                        // [131072,64] same dtype as x
    int* flag = (int*)d_ws;

    const int* src = ei;  // first E entries are the src row

    detect_kernel<<<dim3(1), dim3(64), 0, stream>>>((const unsigned int*)x, flag);

    // 16384 nodes/level, 16 nodes/block -> 1024 blocks of 256 threads
    for (int lvl = 0; lvl < NLEV; ++lvl) {
        hipLaunchKernelGGL(level_kernel, dim3(1024), dim3(256), 0, stream,
                           x, src, Wl, bl, Wr, out, flag, lvl);
    }
}